// Round 19
// baseline (142.902 us; speedup 1.0000x reference)
//
#include <hip/hip_runtime.h>
#include <math.h>

#define NIMG 16
#define A 3
#define HW 65536
#define AHW 196608
#define PRE 2000
#define POST 1000
#define CAP2 2048
#define CAPC 8192
#define MROWS 2048
#define NBUCKET 2048
#define NEGF (-1e30f)
#define LBUF 256
#define BW 0.01f
#define BD 4.0f
#define NQUAD 500      // 2000 rows / 4

__device__ __forceinline__ unsigned mapf(float x) {
    unsigned u = __float_as_uint(x);
    return (u & 0x80000000u) ? ~u : (u | 0x80000000u);
}

// K0: fast zero of the workspace head
__global__ void __launch_bounds__(256) k_zero(uint4* __restrict__ p, int n) {
    int i = blockIdx.x * 256 + threadIdx.x;
    uint4 z; z.x = 0; z.y = 0; z.z = 0; z.w = 0;
    if (i < n) p[i] = z;
}

// K1: per-image histogram of top 11 bits of monotone-mapped objectness (float4 loads)
__global__ void __launch_bounds__(256) k_hist(const float4* __restrict__ obj4,
                                              unsigned* __restrict__ hist) {
    __shared__ unsigned lh[NBUCKET];
    int img = blockIdx.y;
    for (int i = threadIdx.x; i < NBUCKET; i += 256) lh[i] = 0;
    __syncthreads();
    const float4* p = obj4 + (size_t)img * (AHW / 4);
    int stride = gridDim.x * 256;
    for (int v = blockIdx.x * 256 + threadIdx.x; v < AHW / 4; v += stride) {
        float4 f = p[v];
        atomicAdd(&lh[mapf(f.x) >> 21], 1u);
        atomicAdd(&lh[mapf(f.y) >> 21], 1u);
        atomicAdd(&lh[mapf(f.z) >> 21], 1u);
        atomicAdd(&lh[mapf(f.w) >> 21], 1u);
    }
    __syncthreads();
    unsigned* gh = hist + img * NBUCKET;
    for (int i = threadIdx.x; i < NBUCKET; i += 256)
        if (lh[i]) atomicAdd(&gh[i], lh[i]);
}

// Parallel threshold scan: suffix-sum over 256 coarse chunks (Hillis-Steele),
// unique crossing thread does the <=8-bucket descent.
__device__ __forceinline__ void thresh_scan_par(const unsigned* __restrict__ gh,
                                                unsigned cum0,
                                                unsigned* part, unsigned* sfx,
                                                unsigned* outB, unsigned* outCum) {
    int t = threadIdx.x;
    unsigned s = 0;
    for (int k = 0; k < 8; ++k) s += gh[t * 8 + k];
    part[t] = s;
    sfx[t] = s;
    __syncthreads();
    for (int d = 1; d < 256; d <<= 1) {
        unsigned v = (t + d < 256) ? sfx[t + d] : 0u;
        __syncthreads();
        sfx[t] += v;
        __syncthreads();
    }
    unsigned inc = sfx[t], exc = inc - part[t];
    if (cum0 + inc >= PRE && cum0 + exc < PRE) {   // exactly one thread
        unsigned cum = cum0 + exc;
        for (int i = t * 8 + 7; i >= t * 8; --i) {
            unsigned h = gh[i];
            if (cum + h >= PRE) { *outB = (unsigned)i; *outCum = cum; break; }
            cum += h;
        }
    }
}

// K2: coarse threshold bucket B per image + count strictly above B
__global__ void __launch_bounds__(256) k_thresh(const unsigned* __restrict__ hist,
                                                unsigned* __restrict__ bsel,
                                                unsigned* __restrict__ cntAbove) {
    __shared__ unsigned part[256], sfx[256];
    int img = blockIdx.x;
    thresh_scan_par(hist + img * NBUCKET, 0u, part, sfx, &bsel[img], &cntAbove[img]);
}

// K3: COARSE compact: all candidates with m >= B<<21 (~3-4K/img) into coarseK.
// Two-level: LDS staging + one global atomic per block.
__global__ void __launch_bounds__(256) k_compactC(const float4* __restrict__ obj4,
                                                  const unsigned* __restrict__ bsel,
                                                  unsigned* __restrict__ selcntC,
                                                  unsigned long long* __restrict__ coarseK) {
    __shared__ unsigned long long lbuf[LBUF];
    __shared__ unsigned lcnt, gbase;
    int img = blockIdx.y;
    unsigned thr = bsel[img] << 21;
    if (threadIdx.x == 0) lcnt = 0;
    __syncthreads();
    const float4* p = obj4 + (size_t)img * (AHW / 4);
    int v0 = blockIdx.x * 768;
    #pragma unroll
    for (int it = 0; it < 3; ++it) {
        int v = v0 + it * 256 + threadIdx.x;
        float4 f = p[v];
        int jb = v * 4;
        #pragma unroll
        for (int k = 0; k < 4; ++k) {
            float x = k == 0 ? f.x : (k == 1 ? f.y : (k == 2 ? f.z : f.w));
            unsigned m = mapf(x);
            if (m >= thr) {
                int j = jb + k;
                int a = j >> 16;
                int hw = j & 65535;
                unsigned idx = (unsigned)(hw * A + a);
                unsigned pos = atomicAdd(&lcnt, 1u);
                if (pos < LBUF)
                    lbuf[pos] = ((unsigned long long)m << 32) | (unsigned)(~idx);
            }
        }
    }
    __syncthreads();
    unsigned n = lcnt > LBUF ? LBUF : lcnt;
    if (threadIdx.x == 0) gbase = atomicAdd(&selcntC[img * 64], n);
    __syncthreads();
    if (threadIdx.x < n) {
        unsigned pos = gbase + threadIdx.x;
        if (pos < CAPC)
            coarseK[(size_t)img * CAPC + pos] = lbuf[threadIdx.x];
    }
}

// K4: REFINE (fused hist2 + thresh2 + compact2), one block per image.
// Sub-histogram of bucket-B coarse keys in LDS, threshold scan, then compact
// coarse keys with m >= thr into keys[]. Replaces a full 12.6MB atomic scan.
__global__ void __launch_bounds__(256) k_refine(const unsigned long long* __restrict__ coarseK,
                                                const unsigned* __restrict__ selcntC,
                                                const unsigned* __restrict__ bsel,
                                                const unsigned* __restrict__ cntAbove,
                                                unsigned* __restrict__ selcnt,
                                                unsigned long long* __restrict__ keys) {
    __shared__ unsigned lh[NBUCKET];
    __shared__ unsigned part[256], sfx[256];
    __shared__ unsigned thrsh, lcnt;
    int img = blockIdx.x;
    int t = threadIdx.x;
    unsigned B = bsel[img];
    unsigned nC = selcntC[img * 64];
    if (nC > CAPC) nC = CAPC;
    for (int i = t; i < NBUCKET; i += 256) lh[i] = 0;
    if (t == 0) lcnt = 0;
    __syncthreads();
    const unsigned long long* ck = coarseK + (size_t)img * CAPC;
    for (int i = t; i < (int)nC; i += 256) {
        unsigned m = (unsigned)(ck[i] >> 32);
        if ((m >> 21) == B) atomicAdd(&lh[(m >> 10) & 0x7FF], 1u);
    }
    __syncthreads();
    unsigned s = 0;
    for (int k = 0; k < 8; ++k) s += lh[t * 8 + k];
    part[t] = s; sfx[t] = s;
    __syncthreads();
    for (int d = 1; d < 256; d <<= 1) {
        unsigned v = (t + d < 256) ? sfx[t + d] : 0u;
        __syncthreads();
        sfx[t] += v;
        __syncthreads();
    }
    unsigned cum0 = cntAbove[img];
    unsigned inc = sfx[t], exc = inc - part[t];
    if (cum0 + inc >= PRE && cum0 + exc < PRE) {   // exactly one thread
        unsigned cum = cum0 + exc;
        for (int i = t * 8 + 7; i >= t * 8; --i) {
            unsigned h = lh[i];
            if (cum + h >= PRE) { thrsh = (B << 21) | ((unsigned)i << 10); break; }
            cum += h;
        }
    }
    __syncthreads();
    unsigned thr = thrsh;
    for (int i = t; i < (int)nC; i += 256) {
        unsigned long long key = ck[i];
        unsigned m = (unsigned)(key >> 32);
        if (m >= thr) {
            unsigned pos = atomicAdd(&lcnt, 1u);
            if (pos < CAP2) keys[(size_t)img * CAP2 + pos] = key;
        }
    }
    __syncthreads();
    if (t == 0) selcnt[img * 64] = (lcnt > CAP2) ? CAP2 : lcnt;
}

// K5: per-image bitonic sort, descending. Tail beyond the valid count is
// padded with 0 keys in LDS (keys buffer itself is not zeroed).
__global__ void __launch_bounds__(1024) k_sort(unsigned long long* __restrict__ keys,
                                               const unsigned* __restrict__ selcnt) {
    __shared__ unsigned long long s[CAP2];
    int img = blockIdx.x;
    unsigned cnt = selcnt[img * 64];
    if (cnt > CAP2) cnt = CAP2;
    unsigned long long* g = keys + (size_t)img * CAP2;
    for (int i = threadIdx.x; i < CAP2; i += 1024)
        s[i] = (i < (int)cnt) ? g[i] : 0ULL;
    __syncthreads();
    for (int k2 = 2; k2 <= CAP2; k2 <<= 1) {
        for (int j = k2 >> 1; j > 0; j >>= 1) {
            for (int i = threadIdx.x; i < CAP2; i += 1024) {
                int ixj = i ^ j;
                if (ixj > i) {
                    unsigned long long a = s[i], b = s[ixj];
                    bool up = ((i & k2) == 0);
                    if (up ? (a < b) : (a > b)) { s[i] = b; s[ixj] = a; }
                }
            }
            __syncthreads();
        }
    }
    for (int i = threadIdx.x; i < PRE; i += 1024) g[i] = s[i];
}

// K6: decode boxes (f64), clip, MIN_SIZE filter, sigmoid score.
// boxesf is PADDED to MROWS with sentinel boxes (never overlap).
__global__ void k_decode(const float* __restrict__ anchors, const float* __restrict__ br,
                         const unsigned long long* __restrict__ keys,
                         double* __restrict__ boxes, float4* __restrict__ boxesf,
                         float* __restrict__ scores, unsigned* __restrict__ negmask) {
    int g = blockIdx.x * blockDim.x + threadIdx.x;
    if (g >= NIMG * MROWS) return;
    int img = g >> 11, r = g & (MROWS - 1);
    float4* bfp = boxesf + (size_t)img * MROWS + r;
    if (r >= PRE) {
        float4 bf;
        bf.x = 1e8f; bf.y = 1e8f; bf.z = -1e8f; bf.w = -1e8f;
        *bfp = bf;
        return;
    }
    unsigned long long key = keys[(size_t)img * CAP2 + r];
    unsigned m = (unsigned)(key >> 32);
    unsigned idx = ~(unsigned)key;
    unsigned u = (m & 0x80000000u) ? (m ^ 0x80000000u) : ~m;
    float x = __uint_as_float(u);
    double sc = 1.0 / (1.0 + exp(-(double)x));
    int a = idx % 3;
    int hw = idx / 3;
    const float* anc = anchors + ((size_t)img * AHW + idx) * 4;
    double ax1 = anc[0], ay1 = anc[1], ax2 = anc[2], ay2 = anc[3];
    double aw = ax2 - ax1 + 1.0, ah = ay2 - ay1 + 1.0;
    double cx = ax1 + 0.5 * aw, cy = ay1 + 0.5 * ah;
    const float* bp = br + (size_t)img * 12 * HW + (size_t)a * 4 * HW + hw;
    double dx = bp[0];
    double dy = bp[(size_t)HW];
    double dw = bp[(size_t)2 * HW];
    double dh = bp[(size_t)3 * HW];
    const double CLIPV = 4.135166556742356; // log(1000/16)
    dw = fmin(dw, CLIPV); dh = fmin(dh, CLIPV);
    double pcx = dx * aw + cx, pcy = dy * ah + cy;
    double pw = exp(dw) * aw, ph = exp(dh) * ah;
    double x1 = pcx - 0.5 * pw, y1 = pcy - 0.5 * ph;
    double x2 = pcx + 0.5 * pw - 1.0, y2 = pcy + 0.5 * ph - 1.0;
    x1 = fmin(fmax(x1, 0.0), 1023.0);
    y1 = fmin(fmax(y1, 0.0), 1023.0);
    x2 = fmin(fmax(x2, 0.0), 1023.0);
    y2 = fmin(fmax(y2, 0.0), 1023.0);
    bool keep = (x2 - x1 + 1.0 >= 0.0) && (y2 - y1 + 1.0 >= 0.0);
    double* bo = boxes + ((size_t)img * PRE + r) * 4;
    bo[0] = x1; bo[1] = y1; bo[2] = x2; bo[3] = y2;
    float4 bf;
    bf.x = (float)x1; bf.y = (float)y1; bf.z = (float)x2; bf.w = (float)y2;
    *bfp = bf;
    scores[img * PRE + r] = keep ? (float)sc : NEGF;
    if (!keep) atomicOr(&negmask[img * 64 + (r >> 5)], 1u << (r & 31));
}

// strict-upper-triangle trim for row r at lane t (word = cols 32t..32t+31):
// zero bits for cols <= r.
__device__ __forceinline__ unsigned trimask(int r, int t) {
    int cb = 32 * t;
    if (cb + 31 <= r) return 0u;
    if (cb > r) return 0xFFFFFFFFu;
    return 0xFFFFFFFEu << (r & 31);
}

// exact f64 rebuild of one mask row's parity-k words (rare path)
__device__ __noinline__ unsigned fixup_row(const double* __restrict__ base64,
                                           const float4* __restrict__ fb,
                                           int r, int t, int k0,
                                           float4 P, float Arow) {
    const double* ri = base64 + (size_t)r * 4;
    double X1 = ri[0], Y1 = ri[1], X2 = ri[2], Y2 = ri[3];
    double AR = (X2 - X1 + 1.0) * (Y2 - Y1 + 1.0);
    unsigned myw = 0;
    for (int k = k0; k < 32; k += 2) {
        int col = 64 * k + t;
        float4 q = fb[col];
        float Ac = 0.7f * ((q.z - q.x + 1.0f) * (q.w - q.y + 1.0f));
        float iw = fminf(P.z, q.z) - fmaxf(P.x, q.x) + 1.0f;
        float ih = fminf(P.w, q.w) - fmaxf(P.y, q.y) + 1.0f;
        float inter = iw * ih;
        float d = fmaf(1.7f, inter, -(Arow + Ac));
        bool ov = (iw > -BW) & (ih > -BW);
        bool need = ov & ((iw < BW) | (ih < BW) | (fabsf(d) < BD));
        bool res = ov & (d > 0.0f);
        if (need) {   // col < PRE guaranteed (sentinels can't set need)
            const double* rj = base64 + (size_t)col * 4;
            double bX1 = rj[0], bY1 = rj[1], bX2 = rj[2], bY2 = rj[3];
            double IW = fmin(X2, bX2) - fmax(X1, bX1) + 1.0;
            double IH = fmin(Y2, bY2) - fmax(Y1, bY1) + 1.0;
            IW = IW > 0.0 ? IW : 0.0;
            IH = IH > 0.0 ? IH : 0.0;
            double INTER = IW * IH;
            double AJ = (bX2 - bX1 + 1.0) * (bY2 - bY1 + 1.0);
            double IOU = INTER / ((AR + AJ) - INTER);
            res = IOU > 0.7;
        }
        unsigned long long bb = __ballot(res);
        myw = (t == 2 * k) ? (unsigned)bb : myw;
        myw = (t == 2 * k + 1) ? (unsigned)(bb >> 32) : myw;
    }
    return myw;
}

// K7: STRICT upper-triangle IoU suppression bitmask, TRANSPOSED output:
// maskT[img][word t][row r]. Bits for cols <= r zeroed at store time.
#define ROWOP(P, Arow, wreg, nflag)                                \
    {                                                              \
        float iw = fminf(P.z, Q.z) - fmaxf(P.x, Q.x) + 1.0f;       \
        float ih = fminf(P.w, Q.w) - fmaxf(P.y, Q.y) + 1.0f;       \
        float inter = iw * ih;                                     \
        float d = fmaf(1.7f, inter, -(Arow + Ac));                 \
        bool ov = (iw > -BW) & (ih > -BW);                         \
        nflag |= ov & ((iw < BW) | (ih < BW) | (fabsf(d) < BD));   \
        bool res = ov & (d > 0.0f);                                \
        unsigned long long bb = __ballot(res);                     \
        wreg = (t == 2 * k) ? (unsigned)bb : wreg;                 \
        wreg = (t == 2 * k + 1) ? (unsigned)(bb >> 32) : wreg;     \
    }

__global__ void __launch_bounds__(256) k_mask(const float4* __restrict__ boxesf,
                                              const double* __restrict__ boxes,
                                              unsigned* __restrict__ maskT) {
    int img = blockIdx.y;
    int tid = threadIdx.x;
    int wave = tid >> 6, t = tid & 63;
    int wgid = blockIdx.x * 4 + wave;       // 0..499
    int pairIdx = wgid >> 1;                // 0..249
    int khalf = wgid & 1;
    const float4* fb = boxesf + (size_t)img * MROWS;
    const double* base64 = boxes + (size_t)img * PRE * 4;
    unsigned* mtw = maskT + ((size_t)img * 64 + t) * MROWS;
    int tw = t >> 1;
    for (int half = 0; half < 2; ++half) {
        int q = (half == 0) ? pairIdx : (NQUAD - 1 - pairIdx);
        int r0 = q * 4;
        float4 P0 = fb[r0], P1 = fb[r0 + 1], P2 = fb[r0 + 2], P3 = fb[r0 + 3];
        float A0 = 0.7f * ((P0.z - P0.x + 1.0f) * (P0.w - P0.y + 1.0f));
        float A1 = 0.7f * ((P1.z - P1.x + 1.0f) * (P1.w - P1.y + 1.0f));
        float A2 = 0.7f * ((P2.z - P2.x + 1.0f) * (P2.w - P2.y + 1.0f));
        float A3 = 0.7f * ((P3.z - P3.x + 1.0f) * (P3.w - P3.y + 1.0f));
        int kmin = q >> 4;
        int k0 = kmin + ((khalf ^ (kmin & 1)) & 1);   // first k with (k&1)==khalf
        unsigned w0 = 0, w1 = 0, w2 = 0, w3 = 0;
        bool n0 = false, n1 = false, n2 = false, n3 = false;
        for (int k = k0; k < 32; k += 2) {
            int col = 64 * k + t;
            float4 Q = fb[col];
            float Ac = 0.7f * ((Q.z - Q.x + 1.0f) * (Q.w - Q.y + 1.0f));
            ROWOP(P0, A0, w0, n0)
            ROWOP(P1, A1, w1, n1)
            ROWOP(P2, A2, w2, n2)
            ROWOP(P3, A3, w3, n3)
        }
        if (__any(n0)) w0 = fixup_row(base64, fb, r0 + 0, t, k0, P0, A0);
        if (__any(n1)) w1 = fixup_row(base64, fb, r0 + 1, t, k0, P1, A1);
        if (__any(n2)) w2 = fixup_row(base64, fb, r0 + 2, t, k0, P2, A2);
        if (__any(n3)) w3 = fixup_row(base64, fb, r0 + 3, t, k0, P3, A3);
        bool own = (tw >= kmin) && ((tw & 1) == khalf);
        if (own) {
            uint4 v;
            v.x = w0 & trimask(r0 + 0, t);
            v.y = w1 & trimask(r0 + 1, t);
            v.z = w2 & trimask(r0 + 2, t);
            v.w = w3 & trimask(r0 + 3, t);
            *(uint4*)(mtw + r0) = v;    // r0 % 4 == 0 -> 16B aligned
        }
    }
}

// K8: sequential-scan greedy NMS, word-granular (round-18 structure).
#define W_LOAD(B, W) {                                          \
    B[0] = *(const uint4*)(mt + (W) * 32 + 0);                  \
    B[1] = *(const uint4*)(mt + (W) * 32 + 4);                  \
    B[2] = *(const uint4*)(mt + (W) * 32 + 8);                  \
    B[3] = *(const uint4*)(mt + (W) * 32 + 12);                 \
    B[4] = *(const uint4*)(mt + (W) * 32 + 16);                 \
    B[5] = *(const uint4*)(mt + (W) * 32 + 20);                 \
    B[6] = *(const uint4*)(mt + (W) * 32 + 24);                 \
    B[7] = *(const uint4*)(mt + (W) * 32 + 28); }

#define NMS_STEP(BV, S, ACC) {                                  \
    unsigned rb = (unsigned)__builtin_amdgcn_readlane((int)(BV), W); \
    unsigned bit = (s_cur >> (S)) & 1u;                         \
    unsigned am = bit - 1u;  /* alive: ~0, dead: 0 */           \
    s_cur |= rb & am;                                           \
    ACC |= (BV) & am; }

#define NMS_WORD(B, W_) {                                       \
    int W = (W_);                                               \
    unsigned s_cur = (unsigned)__builtin_amdgcn_readlane((int)sup, W); \
    unsigned acc0 = 0, acc1 = 0;                                \
    NMS_STEP(B[0].x, 0, acc0)  NMS_STEP(B[0].y, 1, acc1)        \
    NMS_STEP(B[0].z, 2, acc0)  NMS_STEP(B[0].w, 3, acc1)        \
    NMS_STEP(B[1].x, 4, acc0)  NMS_STEP(B[1].y, 5, acc1)        \
    NMS_STEP(B[1].z, 6, acc0)  NMS_STEP(B[1].w, 7, acc1)        \
    NMS_STEP(B[2].x, 8, acc0)  NMS_STEP(B[2].y, 9, acc1)        \
    NMS_STEP(B[2].z, 10, acc0) NMS_STEP(B[2].w, 11, acc1)       \
    NMS_STEP(B[3].x, 12, acc0) NMS_STEP(B[3].y, 13, acc1)       \
    NMS_STEP(B[3].z, 14, acc0) NMS_STEP(B[3].w, 15, acc1)       \
    NMS_STEP(B[4].x, 16, acc0) NMS_STEP(B[4].y, 17, acc1)       \
    NMS_STEP(B[4].z, 18, acc0) NMS_STEP(B[4].w, 19, acc1)       \
    NMS_STEP(B[5].x, 20, acc0) NMS_STEP(B[5].y, 21, acc1)       \
    NMS_STEP(B[5].z, 22, acc0) NMS_STEP(B[5].w, 23, acc1)       \
    NMS_STEP(B[6].x, 24, acc0) NMS_STEP(B[6].y, 25, acc1)       \
    NMS_STEP(B[6].z, 26, acc0) NMS_STEP(B[6].w, 27, acc1)       \
    NMS_STEP(B[7].x, 28, acc0) NMS_STEP(B[7].y, 29, acc1)       \
    NMS_STEP(B[7].z, 30, acc0) NMS_STEP(B[7].w, 31, acc1)       \
    sup |= acc0 | acc1;                                         \
    unsigned pk = ~s_cur;                                       \
    pickedv = (t == W) ? (int)pk : pickedv;                     \
    np += __builtin_popcount(pk); }

__global__ void __launch_bounds__(64) k_nms(const double* __restrict__ boxes,
                                            const float* __restrict__ scores,
                                            const unsigned* __restrict__ negmask,
                                            const unsigned* __restrict__ maskT,
                                            float* __restrict__ out) {
    __shared__ int picks[POST];
    __shared__ unsigned wcnt[64];
    __shared__ int tot;
    int img = blockIdx.x;
    int t = threadIdx.x;
    unsigned sup = negmask[img * 64 + t];
    if (t == 62) sup |= 0xFFFF0000u;  // indices 2000..2015 invalid
    if (t == 63) sup = 0xFFFFFFFFu;   // indices 2016..2047 invalid
    const unsigned* mt = maskT + ((size_t)img * 64 + t) * MROWS;
    uint4 c0[8], c1[8], c2[8], c3[8];
    W_LOAD(c0, 0) W_LOAD(c1, 1) W_LOAD(c2, 2) W_LOAD(c3, 3)
    __builtin_amdgcn_sched_barrier(0);
    int np = 0;
    int pickedv = 0;
    for (int w = 0; w < 60; w += 4) {
        NMS_WORD(c0, w + 0) W_LOAD(c0, w + 4) __builtin_amdgcn_sched_barrier(0);
        NMS_WORD(c1, w + 1) W_LOAD(c1, w + 5) __builtin_amdgcn_sched_barrier(0);
        NMS_WORD(c2, w + 2) W_LOAD(c2, w + 6) __builtin_amdgcn_sched_barrier(0);
        NMS_WORD(c3, w + 3) W_LOAD(c3, w + 7) __builtin_amdgcn_sched_barrier(0);
        if (np >= POST) break;   // word-aligned; picks truncated in epilogue
    }
    if (np < POST) {
        NMS_WORD(c0, 60) NMS_WORD(c1, 61) NMS_WORD(c2, 62)
    }
    // epilogue: materialize picks[] from the bitmap (lane W holds word W)
    wcnt[t] = (unsigned)__builtin_popcount((unsigned)pickedv);
    __syncthreads();
    int pre = 0;
    for (int i = 0; i < t; ++i) pre += (int)wcnt[i];
    if (t == 63) tot = pre + (int)wcnt[63];
    __syncthreads();
    unsigned pw = (unsigned)pickedv;
    int rank = pre;
    while (pw) {
        int b = __ffs(pw) - 1;
        pw &= pw - 1;
        if (rank < POST) picks[rank] = t * 32 + b;
        rank++;
    }
    __syncthreads();
    int np_final = tot > POST ? POST : tot;
    float* ob = out + (size_t)img * POST * 4;
    float* os = out + (size_t)NIMG * POST * 4 + (size_t)img * POST;
    for (int k = t; k < POST; k += 64) {
        if (k < np_final) {
            int p = picks[k];
            const double* bp = boxes + ((size_t)img * PRE + p) * 4;
            ob[k * 4 + 0] = (float)bp[0];
            ob[k * 4 + 1] = (float)bp[1];
            ob[k * 4 + 2] = (float)bp[2];
            ob[k * 4 + 3] = (float)bp[3];
            os[k] = scores[img * PRE + p];
        } else {
            ob[k * 4 + 0] = 0.0f; ob[k * 4 + 1] = 0.0f;
            ob[k * 4 + 2] = 0.0f; ob[k * 4 + 3] = 0.0f;
            os[k] = NEGF;
        }
    }
}

extern "C" void kernel_launch(void* const* d_in, const int* in_sizes, int n_in,
                              void* d_out, int out_size, void* d_ws, size_t ws_size,
                              hipStream_t stream) {
    const float* anchors = (const float*)d_in[0];
    const float4* obj4 = (const float4*)d_in[1];
    const float* br = (const float*)d_in[2];
    float* out = (float*)d_out;

    char* ws = (char*)d_ws;
    size_t off = 0;
    auto alloc = [&](size_t bytes) {
        void* p = ws + off;
        off = (off + bytes + 255) & ~(size_t)255;
        return p;
    };
    // zero-initialized region (single k_zero dispatch): hist..negmask
    unsigned* hist = (unsigned*)alloc((size_t)NIMG * NBUCKET * 4);
    unsigned* selcntC = (unsigned*)alloc((size_t)NIMG * 64 * 4);     // one cache line per image
    unsigned* negmask = (unsigned*)alloc((size_t)NIMG * 64 * 4);
    size_t zero_bytes = off;   // multiple of 256
    // non-zeroed buffers
    unsigned* bsel = (unsigned*)alloc(NIMG * 4);
    unsigned* cntAbove = (unsigned*)alloc(NIMG * 4);
    unsigned* selcnt = (unsigned*)alloc((size_t)NIMG * 64 * 4);      // written by k_refine
    unsigned long long* coarseK = (unsigned long long*)alloc((size_t)NIMG * CAPC * 8);
    unsigned long long* keys = (unsigned long long*)alloc((size_t)NIMG * CAP2 * 8);
    double* boxes = (double*)alloc((size_t)NIMG * PRE * 4 * 8);
    float4* boxesf = (float4*)alloc((size_t)NIMG * MROWS * 16);
    float* scores = (float*)alloc((size_t)NIMG * PRE * 4);
    unsigned* maskT = (unsigned*)alloc((size_t)NIMG * 64 * MROWS * 4);

    int nzero = (int)(zero_bytes / 16);
    k_zero<<<(nzero + 255) / 256, 256, 0, stream>>>((uint4*)hist, nzero);

    k_hist<<<dim3(64, NIMG), 256, 0, stream>>>(obj4, hist);
    k_thresh<<<NIMG, 256, 0, stream>>>(hist, bsel, cntAbove);
    k_compactC<<<dim3(64, NIMG), 256, 0, stream>>>(obj4, bsel, selcntC, coarseK);
    k_refine<<<NIMG, 256, 0, stream>>>(coarseK, selcntC, bsel, cntAbove, selcnt, keys);
    k_sort<<<NIMG, 1024, 0, stream>>>(keys, selcnt);
    k_decode<<<(NIMG * MROWS + 255) / 256, 256, 0, stream>>>(anchors, br, keys, boxes, boxesf, scores, negmask);
    k_mask<<<dim3(125, NIMG), 256, 0, stream>>>(boxesf, boxes, maskT);
    k_nms<<<NIMG, 64, 0, stream>>>(boxes, scores, negmask, maskT, out);
}

// Round 20
// 140.074 us; speedup vs baseline: 1.0202x; 1.0202x over previous
//
#include <hip/hip_runtime.h>
#include <math.h>

#define NIMG 16
#define A 3
#define HW 65536
#define AHW 196608
#define PRE 2000
#define POST 1000
#define CAP2 2048
#define MROWS 2048
#define NBUCKET 2048
#define NEGF (-1e30f)
#define LBUF 256
#define BW 0.01f
#define BD 4.0f
#define NQUAD 500      // 2000 rows / 4

__device__ __forceinline__ unsigned mapf(float x) {
    unsigned u = __float_as_uint(x);
    return (u & 0x80000000u) ? ~u : (u | 0x80000000u);
}

// K0: fast zero of the workspace head
__global__ void __launch_bounds__(256) k_zero(uint4* __restrict__ p, int n) {
    int i = blockIdx.x * 256 + threadIdx.x;
    uint4 z; z.x = 0; z.y = 0; z.z = 0; z.w = 0;
    if (i < n) p[i] = z;
}

// K1: per-image histogram of top 11 bits of monotone-mapped objectness (float4 loads)
__global__ void __launch_bounds__(256) k_hist(const float4* __restrict__ obj4,
                                              unsigned* __restrict__ hist) {
    __shared__ unsigned lh[NBUCKET];
    int img = blockIdx.y;
    for (int i = threadIdx.x; i < NBUCKET; i += 256) lh[i] = 0;
    __syncthreads();
    const float4* p = obj4 + (size_t)img * (AHW / 4);
    int stride = gridDim.x * 256;
    for (int v = blockIdx.x * 256 + threadIdx.x; v < AHW / 4; v += stride) {
        float4 f = p[v];
        atomicAdd(&lh[mapf(f.x) >> 21], 1u);
        atomicAdd(&lh[mapf(f.y) >> 21], 1u);
        atomicAdd(&lh[mapf(f.z) >> 21], 1u);
        atomicAdd(&lh[mapf(f.w) >> 21], 1u);
    }
    __syncthreads();
    unsigned* gh = hist + img * NBUCKET;
    for (int i = threadIdx.x; i < NBUCKET; i += 256)
        if (lh[i]) atomicAdd(&gh[i], lh[i]);
}

// Parallel threshold scan: suffix-sum over 256 coarse chunks (Hillis-Steele),
// unique crossing thread does the <=8-bucket descent.
__device__ __forceinline__ void thresh_scan_par(const unsigned* __restrict__ gh,
                                                unsigned cum0,
                                                unsigned* part, unsigned* sfx,
                                                unsigned* outB, unsigned* outCum) {
    int t = threadIdx.x;
    unsigned s = 0;
    for (int k = 0; k < 8; ++k) s += gh[t * 8 + k];
    part[t] = s;
    sfx[t] = s;
    __syncthreads();
    for (int d = 1; d < 256; d <<= 1) {
        unsigned v = (t + d < 256) ? sfx[t + d] : 0u;
        __syncthreads();
        sfx[t] += v;
        __syncthreads();
    }
    unsigned inc = sfx[t], exc = inc - part[t];
    if (cum0 + inc >= PRE && cum0 + exc < PRE) {   // exactly one thread
        unsigned cum = cum0 + exc;
        for (int i = t * 8 + 7; i >= t * 8; --i) {
            unsigned h = gh[i];
            if (cum + h >= PRE) { *outB = (unsigned)i; *outCum = cum; break; }
            cum += h;
        }
    }
}

// K2: coarse threshold bucket B per image + count strictly above B
__global__ void __launch_bounds__(256) k_thresh(const unsigned* __restrict__ hist,
                                                unsigned* __restrict__ bsel,
                                                unsigned* __restrict__ cntAbove) {
    __shared__ unsigned part[256], sfx[256];
    int img = blockIdx.x;
    thresh_scan_par(hist + img * NBUCKET, 0u, part, sfx, &bsel[img], &cntAbove[img]);
}

// K3: histogram of next 11 bits within coarse bucket B (float4 loads)
__global__ void __launch_bounds__(256) k_hist2(const float4* __restrict__ obj4,
                                               const unsigned* __restrict__ bsel,
                                               unsigned* __restrict__ hist2) {
    __shared__ unsigned lh[NBUCKET];
    int img = blockIdx.y;
    unsigned B = bsel[img];
    for (int i = threadIdx.x; i < NBUCKET; i += 256) lh[i] = 0;
    __syncthreads();
    const float4* p = obj4 + (size_t)img * (AHW / 4);
    int stride = gridDim.x * 256;
    for (int v = blockIdx.x * 256 + threadIdx.x; v < AHW / 4; v += stride) {
        float4 f = p[v];
        unsigned m0 = mapf(f.x), m1 = mapf(f.y), m2 = mapf(f.z), m3 = mapf(f.w);
        if ((m0 >> 21) == B) atomicAdd(&lh[(m0 >> 10) & 0x7FF], 1u);
        if ((m1 >> 21) == B) atomicAdd(&lh[(m1 >> 10) & 0x7FF], 1u);
        if ((m2 >> 21) == B) atomicAdd(&lh[(m2 >> 10) & 0x7FF], 1u);
        if ((m3 >> 21) == B) atomicAdd(&lh[(m3 >> 10) & 0x7FF], 1u);
    }
    __syncthreads();
    unsigned* gh = hist2 + img * NBUCKET;
    for (int i = threadIdx.x; i < NBUCKET; i += 256)
        if (lh[i]) atomicAdd(&gh[i], lh[i]);
}

// K4: refine to 22-bit threshold
__global__ void __launch_bounds__(256) k_thresh2(const unsigned* __restrict__ hist2,
                                                 const unsigned* __restrict__ bsel,
                                                 const unsigned* __restrict__ cntAbove,
                                                 unsigned* __restrict__ thr32) {
    __shared__ unsigned part[256], sfx[256];
    __shared__ unsigned bk, cumdummy;
    int img = blockIdx.x;
    thresh_scan_par(hist2 + img * NBUCKET, cntAbove[img], part, sfx, &bk, &cumdummy);
    __syncthreads();
    if (threadIdx.x == 0) thr32[img] = (bsel[img] << 21) | (bk << 10);
}

// K5: compact candidates with m >= thr. Two-level: LDS staging + one global
// atomic per block (selcnt padded to a private cache line per image).
__global__ void __launch_bounds__(256) k_compact(const float4* __restrict__ obj4,
                                                 const unsigned* __restrict__ thr32,
                                                 unsigned* __restrict__ selcnt,
                                                 unsigned long long* __restrict__ keys) {
    __shared__ unsigned long long lbuf[LBUF];
    __shared__ unsigned lcnt, gbase;
    int img = blockIdx.y;
    unsigned thr = thr32[img];
    if (threadIdx.x == 0) lcnt = 0;
    __syncthreads();
    const float4* p = obj4 + (size_t)img * (AHW / 4);
    int v0 = blockIdx.x * 768;
    #pragma unroll
    for (int it = 0; it < 3; ++it) {
        int v = v0 + it * 256 + threadIdx.x;
        float4 f = p[v];
        int jb = v * 4;
        #pragma unroll
        for (int k = 0; k < 4; ++k) {
            float x = k == 0 ? f.x : (k == 1 ? f.y : (k == 2 ? f.z : f.w));
            unsigned m = mapf(x);
            if (m >= thr) {
                int j = jb + k;
                int a = j >> 16;
                int hw = j & 65535;
                unsigned idx = (unsigned)(hw * A + a);
                unsigned pos = atomicAdd(&lcnt, 1u);
                if (pos < LBUF)
                    lbuf[pos] = ((unsigned long long)m << 32) | (unsigned)(~idx);
            }
        }
    }
    __syncthreads();
    unsigned n = lcnt > LBUF ? LBUF : lcnt;
    if (threadIdx.x == 0) gbase = atomicAdd(&selcnt[img * 64], n);
    __syncthreads();
    if (threadIdx.x < n) {
        unsigned pos = gbase + threadIdx.x;
        if (pos < CAP2)
            keys[(size_t)img * CAP2 + pos] = lbuf[threadIdx.x];
    }
}

// K6: per-image bitonic sort, descending. Tail beyond the valid count is
// padded with 0 keys in LDS (keys buffer itself is not zeroed).
__global__ void __launch_bounds__(1024) k_sort(unsigned long long* __restrict__ keys,
                                               const unsigned* __restrict__ selcnt) {
    __shared__ unsigned long long s[CAP2];
    int img = blockIdx.x;
    unsigned cnt = selcnt[img * 64];
    if (cnt > CAP2) cnt = CAP2;
    unsigned long long* g = keys + (size_t)img * CAP2;
    for (int i = threadIdx.x; i < CAP2; i += 1024)
        s[i] = (i < (int)cnt) ? g[i] : 0ULL;
    __syncthreads();
    for (int k2 = 2; k2 <= CAP2; k2 <<= 1) {
        for (int j = k2 >> 1; j > 0; j >>= 1) {
            for (int i = threadIdx.x; i < CAP2; i += 1024) {
                int ixj = i ^ j;
                if (ixj > i) {
                    unsigned long long a = s[i], b = s[ixj];
                    bool up = ((i & k2) == 0);
                    if (up ? (a < b) : (a > b)) { s[i] = b; s[ixj] = a; }
                }
            }
            __syncthreads();
        }
    }
    for (int i = threadIdx.x; i < PRE; i += 1024) g[i] = s[i];
}

// K7: decode boxes (f64), clip, MIN_SIZE filter, sigmoid score.
// boxesf is PADDED to MROWS with sentinel boxes (never overlap).
__global__ void k_decode(const float* __restrict__ anchors, const float* __restrict__ br,
                         const unsigned long long* __restrict__ keys,
                         double* __restrict__ boxes, float4* __restrict__ boxesf,
                         float* __restrict__ scores, unsigned* __restrict__ negmask) {
    int g = blockIdx.x * blockDim.x + threadIdx.x;
    if (g >= NIMG * MROWS) return;
    int img = g >> 11, r = g & (MROWS - 1);
    float4* bfp = boxesf + (size_t)img * MROWS + r;
    if (r >= PRE) {
        float4 bf;
        bf.x = 1e8f; bf.y = 1e8f; bf.z = -1e8f; bf.w = -1e8f;
        *bfp = bf;
        return;
    }
    unsigned long long key = keys[(size_t)img * CAP2 + r];
    unsigned m = (unsigned)(key >> 32);
    unsigned idx = ~(unsigned)key;
    unsigned u = (m & 0x80000000u) ? (m ^ 0x80000000u) : ~m;
    float x = __uint_as_float(u);
    double sc = 1.0 / (1.0 + exp(-(double)x));
    int a = idx % 3;
    int hw = idx / 3;
    const float* anc = anchors + ((size_t)img * AHW + idx) * 4;
    double ax1 = anc[0], ay1 = anc[1], ax2 = anc[2], ay2 = anc[3];
    double aw = ax2 - ax1 + 1.0, ah = ay2 - ay1 + 1.0;
    double cx = ax1 + 0.5 * aw, cy = ay1 + 0.5 * ah;
    const float* bp = br + (size_t)img * 12 * HW + (size_t)a * 4 * HW + hw;
    double dx = bp[0];
    double dy = bp[(size_t)HW];
    double dw = bp[(size_t)2 * HW];
    double dh = bp[(size_t)3 * HW];
    const double CLIPV = 4.135166556742356; // log(1000/16)
    dw = fmin(dw, CLIPV); dh = fmin(dh, CLIPV);
    double pcx = dx * aw + cx, pcy = dy * ah + cy;
    double pw = exp(dw) * aw, ph = exp(dh) * ah;
    double x1 = pcx - 0.5 * pw, y1 = pcy - 0.5 * ph;
    double x2 = pcx + 0.5 * pw - 1.0, y2 = pcy + 0.5 * ph - 1.0;
    x1 = fmin(fmax(x1, 0.0), 1023.0);
    y1 = fmin(fmax(y1, 0.0), 1023.0);
    x2 = fmin(fmax(x2, 0.0), 1023.0);
    y2 = fmin(fmax(y2, 0.0), 1023.0);
    bool keep = (x2 - x1 + 1.0 >= 0.0) && (y2 - y1 + 1.0 >= 0.0);
    double* bo = boxes + ((size_t)img * PRE + r) * 4;
    bo[0] = x1; bo[1] = y1; bo[2] = x2; bo[3] = y2;
    float4 bf;
    bf.x = (float)x1; bf.y = (float)y1; bf.z = (float)x2; bf.w = (float)y2;
    *bfp = bf;
    scores[img * PRE + r] = keep ? (float)sc : NEGF;
    if (!keep) atomicOr(&negmask[img * 64 + (r >> 5)], 1u << (r & 31));
}

// strict-upper-triangle trim for row r at lane t (word = cols 32t..32t+31):
// zero bits for cols <= r.
__device__ __forceinline__ unsigned trimask(int r, int t) {
    int cb = 32 * t;
    if (cb + 31 <= r) return 0u;
    if (cb > r) return 0xFFFFFFFFu;
    return 0xFFFFFFFEu << (r & 31);
}

// exact f64 rebuild of one mask row's parity-k words (rare path)
__device__ __noinline__ unsigned fixup_row(const double* __restrict__ base64,
                                           const float4* __restrict__ fb,
                                           int r, int t, int k0,
                                           float4 P, float Arow) {
    const double* ri = base64 + (size_t)r * 4;
    double X1 = ri[0], Y1 = ri[1], X2 = ri[2], Y2 = ri[3];
    double AR = (X2 - X1 + 1.0) * (Y2 - Y1 + 1.0);
    unsigned myw = 0;
    for (int k = k0; k < 32; k += 2) {
        int col = 64 * k + t;
        float4 q = fb[col];
        float Ac = 0.7f * ((q.z - q.x + 1.0f) * (q.w - q.y + 1.0f));
        float iw = fminf(P.z, q.z) - fmaxf(P.x, q.x) + 1.0f;
        float ih = fminf(P.w, q.w) - fmaxf(P.y, q.y) + 1.0f;
        float inter = iw * ih;
        float d = fmaf(1.7f, inter, -(Arow + Ac));
        bool ov = (iw > -BW) & (ih > -BW);
        bool need = ov & ((iw < BW) | (ih < BW) | (fabsf(d) < BD));
        bool res = ov & (d > 0.0f);
        if (need) {   // col < PRE guaranteed (sentinels can't set need)
            const double* rj = base64 + (size_t)col * 4;
            double bX1 = rj[0], bY1 = rj[1], bX2 = rj[2], bY2 = rj[3];
            double IW = fmin(X2, bX2) - fmax(X1, bX1) + 1.0;
            double IH = fmin(Y2, bY2) - fmax(Y1, bY1) + 1.0;
            IW = IW > 0.0 ? IW : 0.0;
            IH = IH > 0.0 ? IH : 0.0;
            double INTER = IW * IH;
            double AJ = (bX2 - bX1 + 1.0) * (bY2 - bY1 + 1.0);
            double IOU = INTER / ((AR + AJ) - INTER);
            res = IOU > 0.7;
        }
        unsigned long long bb = __ballot(res);
        myw = (t == 2 * k) ? (unsigned)bb : myw;
        myw = (t == 2 * k + 1) ? (unsigned)(bb >> 32) : myw;
    }
    return myw;
}

// K8: STRICT upper-triangle IoU suppression bitmask, TRANSPOSED output, with
// one-iteration COLUMN PREFETCH (load fb for k+2 while computing k) to take
// the L1/L2 load off the ROWOP dependency chain.
#define ROWOP(P, Arow, wreg, nflag)                                \
    {                                                              \
        float iw = fminf(P.z, Q.z) - fmaxf(P.x, Q.x) + 1.0f;       \
        float ih = fminf(P.w, Q.w) - fmaxf(P.y, Q.y) + 1.0f;       \
        float inter = iw * ih;                                     \
        float d = fmaf(1.7f, inter, -(Arow + Ac));                 \
        bool ov = (iw > -BW) & (ih > -BW);                         \
        nflag |= ov & ((iw < BW) | (ih < BW) | (fabsf(d) < BD));   \
        bool res = ov & (d > 0.0f);                                \
        unsigned long long bb = __ballot(res);                     \
        wreg = (t == 2 * k) ? (unsigned)bb : wreg;                 \
        wreg = (t == 2 * k + 1) ? (unsigned)(bb >> 32) : wreg;     \
    }

__global__ void __launch_bounds__(256) k_mask(const float4* __restrict__ boxesf,
                                              const double* __restrict__ boxes,
                                              unsigned* __restrict__ maskT) {
    int img = blockIdx.y;
    int tid = threadIdx.x;
    int wave = tid >> 6, t = tid & 63;
    int wgid = blockIdx.x * 4 + wave;       // 0..499
    int pairIdx = wgid >> 1;                // 0..249
    int khalf = wgid & 1;
    const float4* fb = boxesf + (size_t)img * MROWS;
    const double* base64 = boxes + (size_t)img * PRE * 4;
    unsigned* mtw = maskT + ((size_t)img * 64 + t) * MROWS;
    int tw = t >> 1;
    for (int half = 0; half < 2; ++half) {
        int q = (half == 0) ? pairIdx : (NQUAD - 1 - pairIdx);
        int r0 = q * 4;
        float4 P0 = fb[r0], P1 = fb[r0 + 1], P2 = fb[r0 + 2], P3 = fb[r0 + 3];
        float A0 = 0.7f * ((P0.z - P0.x + 1.0f) * (P0.w - P0.y + 1.0f));
        float A1 = 0.7f * ((P1.z - P1.x + 1.0f) * (P1.w - P1.y + 1.0f));
        float A2 = 0.7f * ((P2.z - P2.x + 1.0f) * (P2.w - P2.y + 1.0f));
        float A3 = 0.7f * ((P3.z - P3.x + 1.0f) * (P3.w - P3.y + 1.0f));
        int kmin = q >> 4;
        int k0 = kmin + ((khalf ^ (kmin & 1)) & 1);   // first k with (k&1)==khalf
        unsigned w0 = 0, w1 = 0, w2 = 0, w3 = 0;
        bool n0 = false, n1 = false, n2 = false, n3 = false;
        float4 Qn = fb[64 * k0 + t];          // prefetch first column tile
        for (int k = k0; k < 32; k += 2) {
            float4 Q = Qn;
            int kn = k + 2;
            if (kn < 32) Qn = fb[64 * kn + t];   // prefetch next tile early
            float Ac = 0.7f * ((Q.z - Q.x + 1.0f) * (Q.w - Q.y + 1.0f));
            ROWOP(P0, A0, w0, n0)
            ROWOP(P1, A1, w1, n1)
            ROWOP(P2, A2, w2, n2)
            ROWOP(P3, A3, w3, n3)
        }
        if (__any(n0)) w0 = fixup_row(base64, fb, r0 + 0, t, k0, P0, A0);
        if (__any(n1)) w1 = fixup_row(base64, fb, r0 + 1, t, k0, P1, A1);
        if (__any(n2)) w2 = fixup_row(base64, fb, r0 + 2, t, k0, P2, A2);
        if (__any(n3)) w3 = fixup_row(base64, fb, r0 + 3, t, k0, P3, A3);
        bool own = (tw >= kmin) && ((tw & 1) == khalf);
        if (own) {
            uint4 v;
            v.x = w0 & trimask(r0 + 0, t);
            v.y = w1 & trimask(r0 + 1, t);
            v.z = w2 & trimask(r0 + 2, t);
            v.w = w3 & trimask(r0 + 3, t);
            *(uint4*)(mtw + r0) = v;    // r0 % 4 == 0 -> 16B aligned
        }
    }
}

// K9: sequential-scan greedy NMS, word-granular (round-18 structure).
#define W_LOAD(B, W) {                                          \
    B[0] = *(const uint4*)(mt + (W) * 32 + 0);                  \
    B[1] = *(const uint4*)(mt + (W) * 32 + 4);                  \
    B[2] = *(const uint4*)(mt + (W) * 32 + 8);                  \
    B[3] = *(const uint4*)(mt + (W) * 32 + 12);                 \
    B[4] = *(const uint4*)(mt + (W) * 32 + 16);                 \
    B[5] = *(const uint4*)(mt + (W) * 32 + 20);                 \
    B[6] = *(const uint4*)(mt + (W) * 32 + 24);                 \
    B[7] = *(const uint4*)(mt + (W) * 32 + 28); }

#define NMS_STEP(BV, S, ACC) {                                  \
    unsigned rb = (unsigned)__builtin_amdgcn_readlane((int)(BV), W); \
    unsigned bit = (s_cur >> (S)) & 1u;                         \
    unsigned am = bit - 1u;  /* alive: ~0, dead: 0 */           \
    s_cur |= rb & am;                                           \
    ACC |= (BV) & am; }

#define NMS_WORD(B, W_) {                                       \
    int W = (W_);                                               \
    unsigned s_cur = (unsigned)__builtin_amdgcn_readlane((int)sup, W); \
    unsigned acc0 = 0, acc1 = 0;                                \
    NMS_STEP(B[0].x, 0, acc0)  NMS_STEP(B[0].y, 1, acc1)        \
    NMS_STEP(B[0].z, 2, acc0)  NMS_STEP(B[0].w, 3, acc1)        \
    NMS_STEP(B[1].x, 4, acc0)  NMS_STEP(B[1].y, 5, acc1)        \
    NMS_STEP(B[1].z, 6, acc0)  NMS_STEP(B[1].w, 7, acc1)        \
    NMS_STEP(B[2].x, 8, acc0)  NMS_STEP(B[2].y, 9, acc1)        \
    NMS_STEP(B[2].z, 10, acc0) NMS_STEP(B[2].w, 11, acc1)       \
    NMS_STEP(B[3].x, 12, acc0) NMS_STEP(B[3].y, 13, acc1)       \
    NMS_STEP(B[3].z, 14, acc0) NMS_STEP(B[3].w, 15, acc1)       \
    NMS_STEP(B[4].x, 16, acc0) NMS_STEP(B[4].y, 17, acc1)       \
    NMS_STEP(B[4].z, 18, acc0) NMS_STEP(B[4].w, 19, acc1)       \
    NMS_STEP(B[5].x, 20, acc0) NMS_STEP(B[5].y, 21, acc1)       \
    NMS_STEP(B[5].z, 22, acc0) NMS_STEP(B[5].w, 23, acc1)       \
    NMS_STEP(B[6].x, 24, acc0) NMS_STEP(B[6].y, 25, acc1)       \
    NMS_STEP(B[6].z, 26, acc0) NMS_STEP(B[6].w, 27, acc1)       \
    NMS_STEP(B[7].x, 28, acc0) NMS_STEP(B[7].y, 29, acc1)       \
    NMS_STEP(B[7].z, 30, acc0) NMS_STEP(B[7].w, 31, acc1)       \
    sup |= acc0 | acc1;                                         \
    unsigned pk = ~s_cur;                                       \
    pickedv = (t == W) ? (int)pk : pickedv;                     \
    np += __builtin_popcount(pk); }

__global__ void __launch_bounds__(64) k_nms(const double* __restrict__ boxes,
                                            const float* __restrict__ scores,
                                            const unsigned* __restrict__ negmask,
                                            const unsigned* __restrict__ maskT,
                                            float* __restrict__ out) {
    __shared__ int picks[POST];
    __shared__ unsigned wcnt[64];
    __shared__ int tot;
    int img = blockIdx.x;
    int t = threadIdx.x;
    unsigned sup = negmask[img * 64 + t];
    if (t == 62) sup |= 0xFFFF0000u;  // indices 2000..2015 invalid
    if (t == 63) sup = 0xFFFFFFFFu;   // indices 2016..2047 invalid
    const unsigned* mt = maskT + ((size_t)img * 64 + t) * MROWS;
    uint4 c0[8], c1[8], c2[8], c3[8];
    W_LOAD(c0, 0) W_LOAD(c1, 1) W_LOAD(c2, 2) W_LOAD(c3, 3)
    __builtin_amdgcn_sched_barrier(0);
    int np = 0;
    int pickedv = 0;
    for (int w = 0; w < 60; w += 4) {
        NMS_WORD(c0, w + 0) W_LOAD(c0, w + 4) __builtin_amdgcn_sched_barrier(0);
        NMS_WORD(c1, w + 1) W_LOAD(c1, w + 5) __builtin_amdgcn_sched_barrier(0);
        NMS_WORD(c2, w + 2) W_LOAD(c2, w + 6) __builtin_amdgcn_sched_barrier(0);
        NMS_WORD(c3, w + 3) W_LOAD(c3, w + 7) __builtin_amdgcn_sched_barrier(0);
        if (np >= POST) break;   // word-aligned; picks truncated in epilogue
    }
    if (np < POST) {
        NMS_WORD(c0, 60) NMS_WORD(c1, 61) NMS_WORD(c2, 62)
    }
    // epilogue: materialize picks[] from the bitmap (lane W holds word W)
    wcnt[t] = (unsigned)__builtin_popcount((unsigned)pickedv);
    __syncthreads();
    int pre = 0;
    for (int i = 0; i < t; ++i) pre += (int)wcnt[i];
    if (t == 63) tot = pre + (int)wcnt[63];
    __syncthreads();
    unsigned pw = (unsigned)pickedv;
    int rank = pre;
    while (pw) {
        int b = __ffs(pw) - 1;
        pw &= pw - 1;
        if (rank < POST) picks[rank] = t * 32 + b;
        rank++;
    }
    __syncthreads();
    int np_final = tot > POST ? POST : tot;
    float* ob = out + (size_t)img * POST * 4;
    float* os = out + (size_t)NIMG * POST * 4 + (size_t)img * POST;
    for (int k = t; k < POST; k += 64) {
        if (k < np_final) {
            int p = picks[k];
            const double* bp = boxes + ((size_t)img * PRE + p) * 4;
            ob[k * 4 + 0] = (float)bp[0];
            ob[k * 4 + 1] = (float)bp[1];
            ob[k * 4 + 2] = (float)bp[2];
            ob[k * 4 + 3] = (float)bp[3];
            os[k] = scores[img * PRE + p];
        } else {
            ob[k * 4 + 0] = 0.0f; ob[k * 4 + 1] = 0.0f;
            ob[k * 4 + 2] = 0.0f; ob[k * 4 + 3] = 0.0f;
            os[k] = NEGF;
        }
    }
}

extern "C" void kernel_launch(void* const* d_in, const int* in_sizes, int n_in,
                              void* d_out, int out_size, void* d_ws, size_t ws_size,
                              hipStream_t stream) {
    const float* anchors = (const float*)d_in[0];
    const float4* obj4 = (const float4*)d_in[1];
    const float* br = (const float*)d_in[2];
    float* out = (float*)d_out;

    char* ws = (char*)d_ws;
    size_t off = 0;
    auto alloc = [&](size_t bytes) {
        void* p = ws + off;
        off = (off + bytes + 255) & ~(size_t)255;
        return p;
    };
    // zero-initialized region (single k_zero dispatch): hist..negmask
    unsigned* hist = (unsigned*)alloc((size_t)NIMG * NBUCKET * 4);
    unsigned* hist2 = (unsigned*)alloc((size_t)NIMG * NBUCKET * 4);
    unsigned* bsel = (unsigned*)alloc(NIMG * 4);
    unsigned* cntAbove = (unsigned*)alloc(NIMG * 4);
    unsigned* thr32 = (unsigned*)alloc(NIMG * 4);
    unsigned* selcnt = (unsigned*)alloc((size_t)NIMG * 64 * 4);      // one cache line per image
    unsigned* negmask = (unsigned*)alloc((size_t)NIMG * 64 * 4);
    size_t zero_bytes = off;   // multiple of 256
    // non-zeroed buffers
    unsigned long long* keys = (unsigned long long*)alloc((size_t)NIMG * CAP2 * 8);
    double* boxes = (double*)alloc((size_t)NIMG * PRE * 4 * 8);
    float4* boxesf = (float4*)alloc((size_t)NIMG * MROWS * 16);
    float* scores = (float*)alloc((size_t)NIMG * PRE * 4);
    unsigned* maskT = (unsigned*)alloc((size_t)NIMG * 64 * MROWS * 4);

    int nzero = (int)(zero_bytes / 16);
    k_zero<<<(nzero + 255) / 256, 256, 0, stream>>>((uint4*)hist, nzero);

    k_hist<<<dim3(64, NIMG), 256, 0, stream>>>(obj4, hist);
    k_thresh<<<NIMG, 256, 0, stream>>>(hist, bsel, cntAbove);
    k_hist2<<<dim3(64, NIMG), 256, 0, stream>>>(obj4, bsel, hist2);
    k_thresh2<<<NIMG, 256, 0, stream>>>(hist2, bsel, cntAbove, thr32);
    k_compact<<<dim3(64, NIMG), 256, 0, stream>>>(obj4, thr32, selcnt, keys);
    k_sort<<<NIMG, 1024, 0, stream>>>(keys, selcnt);
    k_decode<<<(NIMG * MROWS + 255) / 256, 256, 0, stream>>>(anchors, br, keys, boxes, boxesf, scores, negmask);
    k_mask<<<dim3(125, NIMG), 256, 0, stream>>>(boxesf, boxes, maskT);
    k_nms<<<NIMG, 64, 0, stream>>>(boxes, scores, negmask, maskT, out);
}

// Round 21
// 137.412 us; speedup vs baseline: 1.0400x; 1.0194x over previous
//
#include <hip/hip_runtime.h>
#include <math.h>

#define NIMG 16
#define A 3
#define HW 65536
#define AHW 196608
#define PRE 2000
#define POST 1000
#define CAP2 2048
#define MROWS 2048
#define NBUCKET 2048
#define NEGF (-1e30f)
#define LBUF 256
#define BW 0.01f
#define BD 4.0f
#define NQUAD 500      // 2000 rows / 4

__device__ __forceinline__ unsigned mapf(float x) {
    unsigned u = __float_as_uint(x);
    return (u & 0x80000000u) ? ~u : (u | 0x80000000u);
}

// K0: fast zero of the workspace head
__global__ void __launch_bounds__(256) k_zero(uint4* __restrict__ p, int n) {
    int i = blockIdx.x * 256 + threadIdx.x;
    uint4 z; z.x = 0; z.y = 0; z.z = 0; z.w = 0;
    if (i < n) p[i] = z;
}

// K1: per-image histogram of top 11 bits of monotone-mapped objectness (float4 loads)
__global__ void __launch_bounds__(256) k_hist(const float4* __restrict__ obj4,
                                              unsigned* __restrict__ hist) {
    __shared__ unsigned lh[NBUCKET];
    int img = blockIdx.y;
    for (int i = threadIdx.x; i < NBUCKET; i += 256) lh[i] = 0;
    __syncthreads();
    const float4* p = obj4 + (size_t)img * (AHW / 4);
    int stride = gridDim.x * 256;
    for (int v = blockIdx.x * 256 + threadIdx.x; v < AHW / 4; v += stride) {
        float4 f = p[v];
        atomicAdd(&lh[mapf(f.x) >> 21], 1u);
        atomicAdd(&lh[mapf(f.y) >> 21], 1u);
        atomicAdd(&lh[mapf(f.z) >> 21], 1u);
        atomicAdd(&lh[mapf(f.w) >> 21], 1u);
    }
    __syncthreads();
    unsigned* gh = hist + img * NBUCKET;
    for (int i = threadIdx.x; i < NBUCKET; i += 256)
        if (lh[i]) atomicAdd(&gh[i], lh[i]);
}

// Parallel threshold scan: suffix-sum over 256 coarse chunks (Hillis-Steele),
// unique crossing thread does the <=8-bucket descent.
__device__ __forceinline__ void thresh_scan_par(const unsigned* __restrict__ gh,
                                                unsigned cum0,
                                                unsigned* part, unsigned* sfx,
                                                unsigned* outB, unsigned* outCum) {
    int t = threadIdx.x;
    unsigned s = 0;
    for (int k = 0; k < 8; ++k) s += gh[t * 8 + k];
    part[t] = s;
    sfx[t] = s;
    __syncthreads();
    for (int d = 1; d < 256; d <<= 1) {
        unsigned v = (t + d < 256) ? sfx[t + d] : 0u;
        __syncthreads();
        sfx[t] += v;
        __syncthreads();
    }
    unsigned inc = sfx[t], exc = inc - part[t];
    if (cum0 + inc >= PRE && cum0 + exc < PRE) {   // exactly one thread
        unsigned cum = cum0 + exc;
        for (int i = t * 8 + 7; i >= t * 8; --i) {
            unsigned h = gh[i];
            if (cum + h >= PRE) { *outB = (unsigned)i; *outCum = cum; break; }
            cum += h;
        }
    }
}

// K2: coarse threshold bucket B per image + count strictly above B
__global__ void __launch_bounds__(256) k_thresh(const unsigned* __restrict__ hist,
                                                unsigned* __restrict__ bsel,
                                                unsigned* __restrict__ cntAbove) {
    __shared__ unsigned part[256], sfx[256];
    int img = blockIdx.x;
    thresh_scan_par(hist + img * NBUCKET, 0u, part, sfx, &bsel[img], &cntAbove[img]);
}

// K3: histogram of next 11 bits within coarse bucket B (float4 loads)
__global__ void __launch_bounds__(256) k_hist2(const float4* __restrict__ obj4,
                                               const unsigned* __restrict__ bsel,
                                               unsigned* __restrict__ hist2) {
    __shared__ unsigned lh[NBUCKET];
    int img = blockIdx.y;
    unsigned B = bsel[img];
    for (int i = threadIdx.x; i < NBUCKET; i += 256) lh[i] = 0;
    __syncthreads();
    const float4* p = obj4 + (size_t)img * (AHW / 4);
    int stride = gridDim.x * 256;
    for (int v = blockIdx.x * 256 + threadIdx.x; v < AHW / 4; v += stride) {
        float4 f = p[v];
        unsigned m0 = mapf(f.x), m1 = mapf(f.y), m2 = mapf(f.z), m3 = mapf(f.w);
        if ((m0 >> 21) == B) atomicAdd(&lh[(m0 >> 10) & 0x7FF], 1u);
        if ((m1 >> 21) == B) atomicAdd(&lh[(m1 >> 10) & 0x7FF], 1u);
        if ((m2 >> 21) == B) atomicAdd(&lh[(m2 >> 10) & 0x7FF], 1u);
        if ((m3 >> 21) == B) atomicAdd(&lh[(m3 >> 10) & 0x7FF], 1u);
    }
    __syncthreads();
    unsigned* gh = hist2 + img * NBUCKET;
    for (int i = threadIdx.x; i < NBUCKET; i += 256)
        if (lh[i]) atomicAdd(&gh[i], lh[i]);
}

// K4: refine to 22-bit threshold
__global__ void __launch_bounds__(256) k_thresh2(const unsigned* __restrict__ hist2,
                                                 const unsigned* __restrict__ bsel,
                                                 const unsigned* __restrict__ cntAbove,
                                                 unsigned* __restrict__ thr32) {
    __shared__ unsigned part[256], sfx[256];
    __shared__ unsigned bk, cumdummy;
    int img = blockIdx.x;
    thresh_scan_par(hist2 + img * NBUCKET, cntAbove[img], part, sfx, &bk, &cumdummy);
    __syncthreads();
    if (threadIdx.x == 0) thr32[img] = (bsel[img] << 21) | (bk << 10);
}

// K5: compact candidates with m >= thr. Two-level: LDS staging + one global
// atomic per block (selcnt padded to a private cache line per image).
__global__ void __launch_bounds__(256) k_compact(const float4* __restrict__ obj4,
                                                 const unsigned* __restrict__ thr32,
                                                 unsigned* __restrict__ selcnt,
                                                 unsigned long long* __restrict__ keys) {
    __shared__ unsigned long long lbuf[LBUF];
    __shared__ unsigned lcnt, gbase;
    int img = blockIdx.y;
    unsigned thr = thr32[img];
    if (threadIdx.x == 0) lcnt = 0;
    __syncthreads();
    const float4* p = obj4 + (size_t)img * (AHW / 4);
    int v0 = blockIdx.x * 768;
    #pragma unroll
    for (int it = 0; it < 3; ++it) {
        int v = v0 + it * 256 + threadIdx.x;
        float4 f = p[v];
        int jb = v * 4;
        #pragma unroll
        for (int k = 0; k < 4; ++k) {
            float x = k == 0 ? f.x : (k == 1 ? f.y : (k == 2 ? f.z : f.w));
            unsigned m = mapf(x);
            if (m >= thr) {
                int j = jb + k;
                int a = j >> 16;
                int hw = j & 65535;
                unsigned idx = (unsigned)(hw * A + a);
                unsigned pos = atomicAdd(&lcnt, 1u);
                if (pos < LBUF)
                    lbuf[pos] = ((unsigned long long)m << 32) | (unsigned)(~idx);
            }
        }
    }
    __syncthreads();
    unsigned n = lcnt > LBUF ? LBUF : lcnt;
    if (threadIdx.x == 0) gbase = atomicAdd(&selcnt[img * 64], n);
    __syncthreads();
    if (threadIdx.x < n) {
        unsigned pos = gbase + threadIdx.x;
        if (pos < CAP2)
            keys[(size_t)img * CAP2 + pos] = lbuf[threadIdx.x];
    }
}

// K6: per-image bitonic sort, descending. Tail beyond the valid count is
// padded with 0 keys in LDS (keys buffer itself is not zeroed).
__global__ void __launch_bounds__(1024) k_sort(unsigned long long* __restrict__ keys,
                                               const unsigned* __restrict__ selcnt) {
    __shared__ unsigned long long s[CAP2];
    int img = blockIdx.x;
    unsigned cnt = selcnt[img * 64];
    if (cnt > CAP2) cnt = CAP2;
    unsigned long long* g = keys + (size_t)img * CAP2;
    for (int i = threadIdx.x; i < CAP2; i += 1024)
        s[i] = (i < (int)cnt) ? g[i] : 0ULL;
    __syncthreads();
    for (int k2 = 2; k2 <= CAP2; k2 <<= 1) {
        for (int j = k2 >> 1; j > 0; j >>= 1) {
            for (int i = threadIdx.x; i < CAP2; i += 1024) {
                int ixj = i ^ j;
                if (ixj > i) {
                    unsigned long long a = s[i], b = s[ixj];
                    bool up = ((i & k2) == 0);
                    if (up ? (a < b) : (a > b)) { s[i] = b; s[ixj] = a; }
                }
            }
            __syncthreads();
        }
    }
    for (int i = threadIdx.x; i < PRE; i += 1024) g[i] = s[i];
}

// K7: decode boxes (f64), clip, MIN_SIZE filter, sigmoid score.
// boxesf is PADDED to MROWS with sentinel boxes (never overlap).
__global__ void k_decode(const float* __restrict__ anchors, const float* __restrict__ br,
                         const unsigned long long* __restrict__ keys,
                         double* __restrict__ boxes, float4* __restrict__ boxesf,
                         float* __restrict__ scores, unsigned* __restrict__ negmask) {
    int g = blockIdx.x * blockDim.x + threadIdx.x;
    if (g >= NIMG * MROWS) return;
    int img = g >> 11, r = g & (MROWS - 1);
    float4* bfp = boxesf + (size_t)img * MROWS + r;
    if (r >= PRE) {
        float4 bf;
        bf.x = 1e8f; bf.y = 1e8f; bf.z = -1e8f; bf.w = -1e8f;
        *bfp = bf;
        return;
    }
    unsigned long long key = keys[(size_t)img * CAP2 + r];
    unsigned m = (unsigned)(key >> 32);
    unsigned idx = ~(unsigned)key;
    unsigned u = (m & 0x80000000u) ? (m ^ 0x80000000u) : ~m;
    float x = __uint_as_float(u);
    double sc = 1.0 / (1.0 + exp(-(double)x));
    int a = idx % 3;
    int hw = idx / 3;
    const float* anc = anchors + ((size_t)img * AHW + idx) * 4;
    double ax1 = anc[0], ay1 = anc[1], ax2 = anc[2], ay2 = anc[3];
    double aw = ax2 - ax1 + 1.0, ah = ay2 - ay1 + 1.0;
    double cx = ax1 + 0.5 * aw, cy = ay1 + 0.5 * ah;
    const float* bp = br + (size_t)img * 12 * HW + (size_t)a * 4 * HW + hw;
    double dx = bp[0];
    double dy = bp[(size_t)HW];
    double dw = bp[(size_t)2 * HW];
    double dh = bp[(size_t)3 * HW];
    const double CLIPV = 4.135166556742356; // log(1000/16)
    dw = fmin(dw, CLIPV); dh = fmin(dh, CLIPV);
    double pcx = dx * aw + cx, pcy = dy * ah + cy;
    double pw = exp(dw) * aw, ph = exp(dh) * ah;
    double x1 = pcx - 0.5 * pw, y1 = pcy - 0.5 * ph;
    double x2 = pcx + 0.5 * pw - 1.0, y2 = pcy + 0.5 * ph - 1.0;
    x1 = fmin(fmax(x1, 0.0), 1023.0);
    y1 = fmin(fmax(y1, 0.0), 1023.0);
    x2 = fmin(fmax(x2, 0.0), 1023.0);
    y2 = fmin(fmax(y2, 0.0), 1023.0);
    bool keep = (x2 - x1 + 1.0 >= 0.0) && (y2 - y1 + 1.0 >= 0.0);
    double* bo = boxes + ((size_t)img * PRE + r) * 4;
    bo[0] = x1; bo[1] = y1; bo[2] = x2; bo[3] = y2;
    float4 bf;
    bf.x = (float)x1; bf.y = (float)y1; bf.z = (float)x2; bf.w = (float)y2;
    *bfp = bf;
    scores[img * PRE + r] = keep ? (float)sc : NEGF;
    if (!keep) atomicOr(&negmask[img * 64 + (r >> 5)], 1u << (r & 31));
}

// strict-upper-triangle trim for row r at lane t (word = cols 32t..32t+31):
// zero bits for cols <= r.
__device__ __forceinline__ unsigned trimask(int r, int t) {
    int cb = 32 * t;
    if (cb + 31 <= r) return 0u;
    if (cb > r) return 0xFFFFFFFFu;
    return 0xFFFFFFFEu << (r & 31);
}

// exact f64 rebuild of one mask row's parity-k words (rare path)
__device__ __noinline__ unsigned fixup_row(const double* __restrict__ base64,
                                           const float4* __restrict__ fb,
                                           int r, int t, int k0,
                                           float4 P, float Arow) {
    const double* ri = base64 + (size_t)r * 4;
    double X1 = ri[0], Y1 = ri[1], X2 = ri[2], Y2 = ri[3];
    double AR = (X2 - X1 + 1.0) * (Y2 - Y1 + 1.0);
    unsigned myw = 0;
    for (int k = k0; k < 32; k += 2) {
        int col = 64 * k + t;
        float4 q = fb[col];
        float Ac = 0.7f * ((q.z - q.x + 1.0f) * (q.w - q.y + 1.0f));
        float iw = fminf(P.z, q.z) - fmaxf(P.x, q.x) + 1.0f;
        float ih = fminf(P.w, q.w) - fmaxf(P.y, q.y) + 1.0f;
        float inter = iw * ih;
        float d = fmaf(1.7f, inter, -(Arow + Ac));
        bool ov = (iw > -BW) & (ih > -BW);
        bool need = ov & ((iw < BW) | (ih < BW) | (fabsf(d) < BD));
        bool res = ov & (d > 0.0f);
        if (need) {   // col < PRE guaranteed (sentinels can't set need)
            const double* rj = base64 + (size_t)col * 4;
            double bX1 = rj[0], bY1 = rj[1], bX2 = rj[2], bY2 = rj[3];
            double IW = fmin(X2, bX2) - fmax(X1, bX1) + 1.0;
            double IH = fmin(Y2, bY2) - fmax(Y1, bY1) + 1.0;
            IW = IW > 0.0 ? IW : 0.0;
            IH = IH > 0.0 ? IH : 0.0;
            double INTER = IW * IH;
            double AJ = (bX2 - bX1 + 1.0) * (bY2 - bY1 + 1.0);
            double IOU = INTER / ((AR + AJ) - INTER);
            res = IOU > 0.7;
        }
        unsigned long long bb = __ballot(res);
        myw = (t == 2 * k) ? (unsigned)bb : myw;
        myw = (t == 2 * k + 1) ? (unsigned)(bb >> 32) : myw;
    }
    return myw;
}

// K8: STRICT upper-triangle IoU suppression bitmask, TRANSPOSED output
// (round-18 form, no prefetch — loads are L1/L2-resident, prefetch regressed).
#define ROWOP(P, Arow, wreg, nflag)                                \
    {                                                              \
        float iw = fminf(P.z, Q.z) - fmaxf(P.x, Q.x) + 1.0f;       \
        float ih = fminf(P.w, Q.w) - fmaxf(P.y, Q.y) + 1.0f;       \
        float inter = iw * ih;                                     \
        float d = fmaf(1.7f, inter, -(Arow + Ac));                 \
        bool ov = (iw > -BW) & (ih > -BW);                         \
        nflag |= ov & ((iw < BW) | (ih < BW) | (fabsf(d) < BD));   \
        bool res = ov & (d > 0.0f);                                \
        unsigned long long bb = __ballot(res);                     \
        wreg = (t == 2 * k) ? (unsigned)bb : wreg;                 \
        wreg = (t == 2 * k + 1) ? (unsigned)(bb >> 32) : wreg;     \
    }

__global__ void __launch_bounds__(256) k_mask(const float4* __restrict__ boxesf,
                                              const double* __restrict__ boxes,
                                              unsigned* __restrict__ maskT) {
    int img = blockIdx.y;
    int tid = threadIdx.x;
    int wave = tid >> 6, t = tid & 63;
    int wgid = blockIdx.x * 4 + wave;       // 0..499
    int pairIdx = wgid >> 1;                // 0..249
    int khalf = wgid & 1;
    const float4* fb = boxesf + (size_t)img * MROWS;
    const double* base64 = boxes + (size_t)img * PRE * 4;
    unsigned* mtw = maskT + ((size_t)img * 64 + t) * MROWS;
    int tw = t >> 1;
    for (int half = 0; half < 2; ++half) {
        int q = (half == 0) ? pairIdx : (NQUAD - 1 - pairIdx);
        int r0 = q * 4;
        float4 P0 = fb[r0], P1 = fb[r0 + 1], P2 = fb[r0 + 2], P3 = fb[r0 + 3];
        float A0 = 0.7f * ((P0.z - P0.x + 1.0f) * (P0.w - P0.y + 1.0f));
        float A1 = 0.7f * ((P1.z - P1.x + 1.0f) * (P1.w - P1.y + 1.0f));
        float A2 = 0.7f * ((P2.z - P2.x + 1.0f) * (P2.w - P2.y + 1.0f));
        float A3 = 0.7f * ((P3.z - P3.x + 1.0f) * (P3.w - P3.y + 1.0f));
        int kmin = q >> 4;
        int k0 = kmin + ((khalf ^ (kmin & 1)) & 1);   // first k with (k&1)==khalf
        unsigned w0 = 0, w1 = 0, w2 = 0, w3 = 0;
        bool n0 = false, n1 = false, n2 = false, n3 = false;
        for (int k = k0; k < 32; k += 2) {
            int col = 64 * k + t;
            float4 Q = fb[col];
            float Ac = 0.7f * ((Q.z - Q.x + 1.0f) * (Q.w - Q.y + 1.0f));
            ROWOP(P0, A0, w0, n0)
            ROWOP(P1, A1, w1, n1)
            ROWOP(P2, A2, w2, n2)
            ROWOP(P3, A3, w3, n3)
        }
        if (__any(n0)) w0 = fixup_row(base64, fb, r0 + 0, t, k0, P0, A0);
        if (__any(n1)) w1 = fixup_row(base64, fb, r0 + 1, t, k0, P1, A1);
        if (__any(n2)) w2 = fixup_row(base64, fb, r0 + 2, t, k0, P2, A2);
        if (__any(n3)) w3 = fixup_row(base64, fb, r0 + 3, t, k0, P3, A3);
        bool own = (tw >= kmin) && ((tw & 1) == khalf);
        if (own) {
            uint4 v;
            v.x = w0 & trimask(r0 + 0, t);
            v.y = w1 & trimask(r0 + 1, t);
            v.z = w2 & trimask(r0 + 2, t);
            v.w = w3 & trimask(r0 + 3, t);
            *(uint4*)(mtw + r0) = v;    // r0 % 4 == 0 -> 16B aligned
        }
    }
}

// K9: sequential-scan greedy NMS, word-granular with BATCHED readlanes:
// all 32 readlanes (VALU->SGPR) issue before the SALU chain, so the
// VALU-writes-SGPR -> SALU-read wait-state is paid once per word, not 32x.
#define W_LOAD(B, W) {                                          \
    B[0] = *(const uint4*)(mt + (W) * 32 + 0);                  \
    B[1] = *(const uint4*)(mt + (W) * 32 + 4);                  \
    B[2] = *(const uint4*)(mt + (W) * 32 + 8);                  \
    B[3] = *(const uint4*)(mt + (W) * 32 + 12);                 \
    B[4] = *(const uint4*)(mt + (W) * 32 + 16);                 \
    B[5] = *(const uint4*)(mt + (W) * 32 + 20);                 \
    B[6] = *(const uint4*)(mt + (W) * 32 + 24);                 \
    B[7] = *(const uint4*)(mt + (W) * 32 + 28); }

#define RL(x) ((unsigned)__builtin_amdgcn_readlane((int)(x), W))

#define NMS_STEP(S, RB, BV, ACC) {                              \
    unsigned bit = (s_cur >> (S)) & 1u;                         \
    unsigned am = bit - 1u;  /* alive: ~0, dead: 0 */           \
    s_cur |= (RB) & am;                                         \
    ACC |= (BV) & am; }

#define NMS_WORD(B, W_) {                                       \
    int W = (W_);                                               \
    unsigned q0 = RL(B[0].x), q1 = RL(B[0].y), q2 = RL(B[0].z), q3 = RL(B[0].w); \
    unsigned q4 = RL(B[1].x), q5 = RL(B[1].y), q6 = RL(B[1].z), q7 = RL(B[1].w); \
    unsigned q8 = RL(B[2].x), q9 = RL(B[2].y), q10 = RL(B[2].z), q11 = RL(B[2].w); \
    unsigned q12 = RL(B[3].x), q13 = RL(B[3].y), q14 = RL(B[3].z), q15 = RL(B[3].w); \
    unsigned q16 = RL(B[4].x), q17 = RL(B[4].y), q18 = RL(B[4].z), q19 = RL(B[4].w); \
    unsigned q20 = RL(B[5].x), q21 = RL(B[5].y), q22 = RL(B[5].z), q23 = RL(B[5].w); \
    unsigned q24 = RL(B[6].x), q25 = RL(B[6].y), q26 = RL(B[6].z), q27 = RL(B[6].w); \
    unsigned q28 = RL(B[7].x), q29 = RL(B[7].y), q30 = RL(B[7].z), q31 = RL(B[7].w); \
    unsigned s_cur = RL(sup);                                   \
    unsigned acc0 = 0, acc1 = 0;                                \
    NMS_STEP(0, q0, B[0].x, acc0)   NMS_STEP(1, q1, B[0].y, acc1) \
    NMS_STEP(2, q2, B[0].z, acc0)   NMS_STEP(3, q3, B[0].w, acc1) \
    NMS_STEP(4, q4, B[1].x, acc0)   NMS_STEP(5, q5, B[1].y, acc1) \
    NMS_STEP(6, q6, B[1].z, acc0)   NMS_STEP(7, q7, B[1].w, acc1) \
    NMS_STEP(8, q8, B[2].x, acc0)   NMS_STEP(9, q9, B[2].y, acc1) \
    NMS_STEP(10, q10, B[2].z, acc0) NMS_STEP(11, q11, B[2].w, acc1) \
    NMS_STEP(12, q12, B[3].x, acc0) NMS_STEP(13, q13, B[3].y, acc1) \
    NMS_STEP(14, q14, B[3].z, acc0) NMS_STEP(15, q15, B[3].w, acc1) \
    NMS_STEP(16, q16, B[4].x, acc0) NMS_STEP(17, q17, B[4].y, acc1) \
    NMS_STEP(18, q18, B[4].z, acc0) NMS_STEP(19, q19, B[4].w, acc1) \
    NMS_STEP(20, q20, B[5].x, acc0) NMS_STEP(21, q21, B[5].y, acc1) \
    NMS_STEP(22, q22, B[5].z, acc0) NMS_STEP(23, q23, B[5].w, acc1) \
    NMS_STEP(24, q24, B[6].x, acc0) NMS_STEP(25, q25, B[6].y, acc1) \
    NMS_STEP(26, q26, B[6].z, acc0) NMS_STEP(27, q27, B[6].w, acc1) \
    NMS_STEP(28, q28, B[7].x, acc0) NMS_STEP(29, q29, B[7].y, acc1) \
    NMS_STEP(30, q30, B[7].z, acc0) NMS_STEP(31, q31, B[7].w, acc1) \
    sup |= acc0 | acc1;                                         \
    unsigned pk = ~s_cur;                                       \
    pickedv = (t == W) ? (int)pk : pickedv;                     \
    np += __builtin_popcount(pk); }

__global__ void __launch_bounds__(64) k_nms(const double* __restrict__ boxes,
                                            const float* __restrict__ scores,
                                            const unsigned* __restrict__ negmask,
                                            const unsigned* __restrict__ maskT,
                                            float* __restrict__ out) {
    __shared__ int picks[POST];
    __shared__ unsigned wcnt[64];
    __shared__ int tot;
    int img = blockIdx.x;
    int t = threadIdx.x;
    unsigned sup = negmask[img * 64 + t];
    if (t == 62) sup |= 0xFFFF0000u;  // indices 2000..2015 invalid
    if (t == 63) sup = 0xFFFFFFFFu;   // indices 2016..2047 invalid
    const unsigned* mt = maskT + ((size_t)img * 64 + t) * MROWS;
    uint4 c0[8], c1[8], c2[8], c3[8];
    W_LOAD(c0, 0) W_LOAD(c1, 1) W_LOAD(c2, 2) W_LOAD(c3, 3)
    __builtin_amdgcn_sched_barrier(0);
    int np = 0;
    int pickedv = 0;
    for (int w = 0; w < 60; w += 4) {
        NMS_WORD(c0, w + 0) W_LOAD(c0, w + 4) __builtin_amdgcn_sched_barrier(0);
        NMS_WORD(c1, w + 1) W_LOAD(c1, w + 5) __builtin_amdgcn_sched_barrier(0);
        NMS_WORD(c2, w + 2) W_LOAD(c2, w + 6) __builtin_amdgcn_sched_barrier(0);
        NMS_WORD(c3, w + 3) W_LOAD(c3, w + 7) __builtin_amdgcn_sched_barrier(0);
        if (np >= POST) break;   // word-aligned; picks truncated in epilogue
    }
    if (np < POST) {
        NMS_WORD(c0, 60) NMS_WORD(c1, 61) NMS_WORD(c2, 62)
    }
    // epilogue: materialize picks[] from the bitmap (lane W holds word W)
    wcnt[t] = (unsigned)__builtin_popcount((unsigned)pickedv);
    __syncthreads();
    int pre = 0;
    for (int i = 0; i < t; ++i) pre += (int)wcnt[i];
    if (t == 63) tot = pre + (int)wcnt[63];
    __syncthreads();
    unsigned pw = (unsigned)pickedv;
    int rank = pre;
    while (pw) {
        int b = __ffs(pw) - 1;
        pw &= pw - 1;
        if (rank < POST) picks[rank] = t * 32 + b;
        rank++;
    }
    __syncthreads();
    int np_final = tot > POST ? POST : tot;
    float* ob = out + (size_t)img * POST * 4;
    float* os = out + (size_t)NIMG * POST * 4 + (size_t)img * POST;
    for (int k = t; k < POST; k += 64) {
        if (k < np_final) {
            int p = picks[k];
            const double* bp = boxes + ((size_t)img * PRE + p) * 4;
            ob[k * 4 + 0] = (float)bp[0];
            ob[k * 4 + 1] = (float)bp[1];
            ob[k * 4 + 2] = (float)bp[2];
            ob[k * 4 + 3] = (float)bp[3];
            os[k] = scores[img * PRE + p];
        } else {
            ob[k * 4 + 0] = 0.0f; ob[k * 4 + 1] = 0.0f;
            ob[k * 4 + 2] = 0.0f; ob[k * 4 + 3] = 0.0f;
            os[k] = NEGF;
        }
    }
}

extern "C" void kernel_launch(void* const* d_in, const int* in_sizes, int n_in,
                              void* d_out, int out_size, void* d_ws, size_t ws_size,
                              hipStream_t stream) {
    const float* anchors = (const float*)d_in[0];
    const float4* obj4 = (const float4*)d_in[1];
    const float* br = (const float*)d_in[2];
    float* out = (float*)d_out;

    char* ws = (char*)d_ws;
    size_t off = 0;
    auto alloc = [&](size_t bytes) {
        void* p = ws + off;
        off = (off + bytes + 255) & ~(size_t)255;
        return p;
    };
    // zero-initialized region (single k_zero dispatch): hist..negmask
    unsigned* hist = (unsigned*)alloc((size_t)NIMG * NBUCKET * 4);
    unsigned* hist2 = (unsigned*)alloc((size_t)NIMG * NBUCKET * 4);
    unsigned* bsel = (unsigned*)alloc(NIMG * 4);
    unsigned* cntAbove = (unsigned*)alloc(NIMG * 4);
    unsigned* thr32 = (unsigned*)alloc(NIMG * 4);
    unsigned* selcnt = (unsigned*)alloc((size_t)NIMG * 64 * 4);      // one cache line per image
    unsigned* negmask = (unsigned*)alloc((size_t)NIMG * 64 * 4);
    size_t zero_bytes = off;   // multiple of 256
    // non-zeroed buffers
    unsigned long long* keys = (unsigned long long*)alloc((size_t)NIMG * CAP2 * 8);
    double* boxes = (double*)alloc((size_t)NIMG * PRE * 4 * 8);
    float4* boxesf = (float4*)alloc((size_t)NIMG * MROWS * 16);
    float* scores = (float*)alloc((size_t)NIMG * PRE * 4);
    unsigned* maskT = (unsigned*)alloc((size_t)NIMG * 64 * MROWS * 4);

    int nzero = (int)(zero_bytes / 16);
    k_zero<<<(nzero + 255) / 256, 256, 0, stream>>>((uint4*)hist, nzero);

    k_hist<<<dim3(64, NIMG), 256, 0, stream>>>(obj4, hist);
    k_thresh<<<NIMG, 256, 0, stream>>>(hist, bsel, cntAbove);
    k_hist2<<<dim3(64, NIMG), 256, 0, stream>>>(obj4, bsel, hist2);
    k_thresh2<<<NIMG, 256, 0, stream>>>(hist2, bsel, cntAbove, thr32);
    k_compact<<<dim3(64, NIMG), 256, 0, stream>>>(obj4, thr32, selcnt, keys);
    k_sort<<<NIMG, 1024, 0, stream>>>(keys, selcnt);
    k_decode<<<(NIMG * MROWS + 255) / 256, 256, 0, stream>>>(anchors, br, keys, boxes, boxesf, scores, negmask);
    k_mask<<<dim3(125, NIMG), 256, 0, stream>>>(boxesf, boxes, maskT);
    k_nms<<<NIMG, 64, 0, stream>>>(boxes, scores, negmask, maskT, out);
}